// Round 1
// baseline (1957.868 us; speedup 1.0000x reference)
//
#include <hip/hip_runtime.h>

// ---- problem constants ----
#define kB 4
#define kV 2
#define kS 256
#define kW 32
#define kM 16
#define kNB 6
#define kTIN 10
#define kSTEP 5

#define NPLANE 65536            // S*S
#define NBWV   (kB*kW*kV)       // 256
#define BIGN   (kB*kW*kV*NPLANE)// 16777216 floats per state buffer
#define CHS    (kV*NPLANE)      // channel stride = 131072

// ---- workspace layout (float offsets) ----
#define OFF_BIG0 0
#define OFF_BIG1 16777216
#define OFF_BIG2 33554432
#define OFF_FYR  50331648   // [bwv][ky16][x256] = 1048576
#define OFF_FYI  51380224
#define OFF_FXR  52428800   // [b][ch][v][ky16][j32] = 131072
#define OFF_FXI  52559872
#define OFF_GR   52690944
#define OFF_GI   52822016
#define OFF_TXC  52953088   // xdft fwd [x][j]  8192
#define OFF_TXS  52961280
#define OFF_TIC  52969472   // x inverse [j][x] 8192
#define OFF_TIS  52977664
#define OFF_IYC  52985856   // y inverse [k][y] 4096
#define OFF_IYS  52989952
// total 52994048 floats ~= 202 MiB

__device__ __forceinline__ float gelu_f(float x){
    return 0.5f*x*(1.0f+erff(x*0.7071067811865476f));
}

// ---- DFT tables (double trig for accuracy, computed on device each launch) ----
__global__ void k_tables(float* ws){
    const double PI = 3.14159265358979323846;
    int t = blockIdx.x*256 + threadIdx.x; // 8192 threads
    if (t < 8192){
        // forward x-DFT, [x][j]: e^{-i 2pi kx x /256}
        int x = t>>5, j = t&31;
        int kx = (j<16) ? j : (224+j);
        int p = (kx*x)&255;
        double a = (double)p*(PI/128.0);
        ws[OFF_TXC+t] = (float)cos(a);
        ws[OFF_TXS+t] = -(float)sin(a);
        // inverse x-DFT, [j][x]: e^{+i 2pi kx x /256}
        int j2 = t>>8, x2 = t&255;
        int kx2 = (j2<16) ? j2 : (224+j2);
        int p2 = (kx2*x2)&255;
        double a2 = (double)p2*(PI/128.0);
        ws[OFF_TIC+t] = (float)cos(a2);
        ws[OFF_TIS+t] = (float)sin(a2);
    }
    if (t < 4096){
        // y-irfft basis [k][y], scale 1/65536 folds both ifft normalizations
        int k = t>>8, y = t&255;
        int p = (k*y)&255;
        double a = (double)p*(PI/128.0);
        float sc = 1.0f/65536.0f;
        ws[OFF_IYC+t] = (k==0 ? 1.0f : 2.0f*(float)cos(a))*sc;
        ws[OFF_IYS+t] = (k==0 ? 0.0f : -2.0f*(float)sin(a))*sc;
    }
}

// ---- fc0 + grid concat + transpose to (B,W,V,S,S) ----
__global__ void k_fc0(const float* __restrict__ x, const float* __restrict__ w,
                      const float* __restrict__ bias, float* __restrict__ h0){
    __shared__ float wl[12*32];
    __shared__ float bl[32];
    int tid = threadIdx.x;
    for (int i=tid;i<384;i+=256) wl[i]=w[i];
    if (tid<32) bl[tid]=bias[tid];
    __syncthreads();
    int plane = blockIdx.x>>8, xr = blockIdx.x&255, y = tid;
    int xy = xr*256+y;
    long p = (long)plane*NPLANE + xy;
    float f[12];
    #pragma unroll
    for (int i=0;i<10;i++) f[i]=x[p*10+i];
    f[10] = 9.5f + xr*(1.0f/255.0f);
    f[11] = -0.5f + y*(1.0f/255.0f);
    float acc[32];
    #pragma unroll
    for (int o=0;o<32;o++) acc[o]=bl[o];
    #pragma unroll
    for (int c=0;c<12;c++){
        float fv=f[c];
        #pragma unroll
        for (int o=0;o<32;o++) acc[o]+=fv*wl[c*32+o];
    }
    int b=plane>>1, v=plane&1;
    int base = b*(kW*CHS) + v*NPLANE + xy;
    #pragma unroll
    for (int o=0;o<32;o++) h0[base + o*CHS]=acc[o];
}

// ---- forward y-DFT: h (bwv,x,y) -> Fy[bwv][ky][x], rotation recurrence ----
__global__ void k_ydft(const float* __restrict__ h, float* __restrict__ fyr, float* __restrict__ fyi){
    __shared__ float hl[16*257];
    __shared__ float rr[16*17], ri[16*17];
    const double PI = 3.14159265358979323846;
    int bwv = blockIdx.x>>4, x0 = (blockIdx.x&15)<<4;
    int tid = threadIdx.x;
    const float* src = h + bwv*NPLANE + x0*256;
    for (int l=tid;l<4096;l+=256) hl[(l>>8)*257+(l&255)] = src[l];
    __syncthreads();
    int xi = tid>>4, k = tid&15;
    double a = (double)k*(PI/128.0);
    float cs = (float)cos(a), sn = -(float)sin(a); // step e^{-i 2pi k/256}
    float c = 1.0f, s = 0.0f, re = 0.0f, im = 0.0f;
    const float* row = hl + xi*257;
    #pragma unroll 8
    for (int y=0;y<256;y++){
        float av = row[y];
        re += av*c; im += av*s;
        float c2 = c*cs - s*sn;
        s = c*sn + s*cs; c = c2;
    }
    rr[xi*17+k]=re; ri[xi*17+k]=im;
    __syncthreads();
    int k2 = tid>>4, xi2 = tid&15;
    int o = bwv*4096 + k2*256 + x0+xi2;
    fyr[o]=rr[xi2*17+k2]; fyi[o]=ri[xi2*17+k2];
}

// ---- forward x-DFT: Fy row (256 x complex) -> 32 kx modes ----
__global__ void k_xdft(const float* __restrict__ fyr, const float* __restrict__ fyi,
                       const float* __restrict__ tab, float* __restrict__ fxr, float* __restrict__ fxi){
    int gid = blockIdx.x*256+threadIdx.x; // 131072
    int r = gid>>5, j = gid&31;
    const float* ar = fyr + r*256;
    const float* ai = fyi + r*256;
    const float* xc = tab;          // [x][j]
    const float* xs = tab + 8192;   // -sin
    float re=0.f, im=0.f;
    #pragma unroll 4
    for (int x=0;x<256;x++){
        float a=ar[x], b=ai[x];
        float c=xc[x*32+j], s=xs[x*32+j];
        re += a*c - b*s;
        im += a*s + b*c;
    }
    int o = ((r>>4)<<9) + ((r&15)<<5) + j; // [bwv][ky][j]
    fxr[o]=re; fxi[o]=im;
}

// ---- complex mode mixing with w1 (kx<16) / w2 (kx>=240) ----
__global__ void k_modemix(const float* __restrict__ fxr, const float* __restrict__ fxi,
                          const float* __restrict__ w1r_, const float* __restrict__ w1i_,
                          const float* __restrict__ w2r_, const float* __restrict__ w2i_,
                          float* __restrict__ gr, float* __restrict__ gi){
    int gid = blockIdx.x*256+threadIdx.x; // 131072: [b][o][v][ky][j]
    int j = gid&31, ky=(gid>>5)&15, v=(gid>>9)&1, o=(gid>>10)&31, b=gid>>15;
    int kxi = (j<16) ? j : (j-16);
    const float* wr_ = (j<16) ? w1r_ : w2r_;
    const float* wi_ = (j<16) ? w1i_ : w2i_;
    int wbase = (o*kV + v)*256 + kxi*16 + ky;         // + i*16384
    int fbase = (b*kW*kV + v)*512 + ky*32 + j;        // + i*1024
    float re=0.f, im=0.f;
    #pragma unroll 8
    for (int i=0;i<32;i++){
        float fr=fxr[fbase+i*1024], fi=fxi[fbase+i*1024];
        float wr=wr_[wbase+i*16384], wi=wi_[wbase+i*16384];
        re += fr*wr - fi*wi;
        im += fr*wi + fi*wr;
    }
    gr[gid]=re; gi[gid]=im;
}

// ---- fold mlp1 (channel-linear) into Fourier domain ----
__global__ void k_mlp1mix(const float* __restrict__ gr, const float* __restrict__ gi,
                          const float* __restrict__ m1, float* __restrict__ g2r, float* __restrict__ g2i){
    int gid = blockIdx.x*256+threadIdx.x; // 131072
    int r = gid & 1023;        // (v,ky,j)
    int o2 = (gid>>10)&31;
    int b = gid>>15;
    int base = b*32768 + r;
    float re=0.f, im=0.f;
    #pragma unroll 8
    for (int i=0;i<32;i++){
        float m = m1[o2*32+i];
        re += m*gr[base+i*1024];
        im += m*gi[base+i*1024];
    }
    g2r[gid]=re; g2i[gid]=im;
}

// ---- fused inverse: x-iDFT (32 modes) + y-irfft (16 modes) + mlp1 bias + gelu ----
__global__ void k_invfft(const float* __restrict__ g2r, const float* __restrict__ g2i,
                         const float* __restrict__ xic, const float* __restrict__ xis,
                         const float* __restrict__ iyc, const float* __restrict__ iys,
                         const float* __restrict__ b1, float* __restrict__ tout){
    __shared__ float fr[16], fi[16];
    int bwv = blockIdx.x>>8, x = blockIdx.x&255;
    int tid = threadIdx.x;
    if (tid < 16){
        int k = tid;
        const float* g_r = g2r + bwv*512 + k*32;
        const float* g_i = g2i + bwv*512 + k*32;
        float re=0.f, im=0.f;
        #pragma unroll
        for (int j=0;j<32;j++){
            float gr=g_r[j], gi=g_i[j];
            float c=xic[j*256+x], s=xis[j*256+x]; // e^{+i theta}
            re += gr*c - gi*s;
            im += gr*s + gi*c;
        }
        fr[k]=re; fi[k]=im;
    }
    __syncthreads();
    int w = (bwv>>1)&31;
    float bias = b1[w];
    int y = tid;
    float acc = bias;
    #pragma unroll
    for (int k=0;k<16;k++){
        acc += fr[k]*iyc[k*256+y] + fi[k]*iys[k*256+y]; // Im(F0) dropped via iys[0]=0
    }
    tout[bwv*NPLANE + x*256 + y] = gelu_f(acc);
}

// ---- fused pointwise: mlp2(t) + ww*h + grid-term, gelu, optional residual ----
// NOTE: out may equal h (in-place). No __restrict__ on h/out.
__global__ void k_pointmix(const float* __restrict__ t, const float* h, const float* res, float* out,
                           const float* __restrict__ m2, const float* __restrict__ b2,
                           const float* __restrict__ ww_, const float* __restrict__ wb_,
                           const float* __restrict__ bw_, const float* __restrict__ bb_){
    __shared__ float w2l[1024], wwl[1024];
    __shared__ float cinit[32], bwx[32], bwy[32];
    int tid = threadIdx.x;
    for (int l=tid;l<1024;l+=256){
        int o=l>>5, c=l&31;
        w2l[c*32+o]=m2[l];   // transpose [o][c] -> [c][o]
        wwl[c*32+o]=ww_[l];
    }
    if (tid<32){
        cinit[tid]=b2[tid]+wb_[tid]+bb_[tid];
        bwx[tid]=bw_[tid*2]; bwy[tid]=bw_[tid*2+1];
    }
    __syncthreads();
    int plane=blockIdx.x>>8, xr=blockIdx.x&255, y=tid;
    int b=plane>>1, v=plane&1, xy=xr*256+y;
    int pbase = b*(kW*CHS) + v*NPLANE + xy;
    float gx = 9.5f + xr*(1.0f/255.0f);
    float gy = -0.5f + y*(1.0f/255.0f);
    float acc[32];
    #pragma unroll
    for (int o=0;o<32;o++) acc[o]=cinit[o]+bwx[o]*gx+bwy[o]*gy;
    #pragma unroll 4
    for (int c=0;c<32;c++){
        float tv=t[pbase + c*CHS];
        #pragma unroll
        for (int o=0;o<32;o++) acc[o]+=tv*w2l[c*32+o];
    }
    #pragma unroll 4
    for (int c=0;c<32;c++){
        float hv=h[pbase + c*CHS];
        #pragma unroll
        for (int o=0;o<32;o++) acc[o]+=hv*wwl[c*32+o];
    }
    if (res){
        #pragma unroll
        for (int o=0;o<32;o++) out[pbase+o*CHS]=gelu_f(acc[o])+res[pbase+o*CHS];
    } else {
        #pragma unroll
        for (int o=0;o<32;o++) out[pbase+o*CHS]=gelu_f(acc[o]);
    }
}

// ---- head: fc1(32->256) + gelu + fc2(256->5), fused ----
__global__ void k_head(const float* __restrict__ h, const float* __restrict__ fc1w,
                       const float* __restrict__ fc1b, const float* __restrict__ fc2w,
                       const float* __restrict__ fc2b, float* __restrict__ out){
    __shared__ float w1l[256*40]; // [o][c] padded to 40 (16B-aligned rows)
    __shared__ float b1l[256];
    __shared__ float w2l[256*5];
    int tid = threadIdx.x;
    for (int l=tid;l<8192;l+=256){
        int c=l>>8, o=l&255;
        w1l[o*40+c]=fc1w[l]; // fc1w is [c][o]
    }
    b1l[tid]=fc1b[tid];
    for (int l=tid;l<1280;l+=256) w2l[l]=fc2w[l];
    __syncthreads();
    int plane=blockIdx.x>>8, xr=blockIdx.x&255, y=tid;
    int b=plane>>1, v=plane&1, xy=xr*256+y;
    int pbase = b*(kW*CHS) + v*NPLANE + xy;
    float hv[32];
    #pragma unroll
    for (int c=0;c<32;c++) hv[c]=h[pbase+c*CHS];
    float acc5[5];
    #pragma unroll
    for (int j=0;j<5;j++) acc5[j]=fc2b[j];
    #pragma unroll 2
    for (int o=0;o<256;o++){
        float s=b1l[o];
        const float* wrow = w1l + o*40;
        #pragma unroll
        for (int c=0;c<32;c++) s+=hv[c]*wrow[c];
        s=gelu_f(s);
        #pragma unroll
        for (int j=0;j<5;j++) acc5[j]+=s*w2l[o*5+j];
    }
    long obase = ((long)plane*NPLANE + xy)*5;
    #pragma unroll
    for (int j=0;j<5;j++) out[obase+j]=acc5[j];
}

extern "C" void kernel_launch(void* const* d_in, const int* in_sizes, int n_in,
                              void* d_out, int out_size, void* d_ws, size_t ws_size,
                              hipStream_t stream){
    const float* x    =(const float*)d_in[0];
    const float* fc0w =(const float*)d_in[1];
    const float* fc0b =(const float*)d_in[2];
    const float* w1r  =(const float*)d_in[3];
    const float* w1i  =(const float*)d_in[4];
    const float* w2r  =(const float*)d_in[5];
    const float* w2i  =(const float*)d_in[6];
    const float* m1w  =(const float*)d_in[7];
    const float* m1b  =(const float*)d_in[8];
    const float* m2w  =(const float*)d_in[9];
    const float* m2b  =(const float*)d_in[10];
    const float* ww   =(const float*)d_in[11];
    const float* wb   =(const float*)d_in[12];
    const float* bw   =(const float*)d_in[13];
    const float* bb   =(const float*)d_in[14];
    const float* fc1w =(const float*)d_in[15];
    const float* fc1b =(const float*)d_in[16];
    const float* fc2w =(const float*)d_in[17];
    const float* fc2b =(const float*)d_in[18];

    float* ws = (float*)d_ws;
    float* big[3] = {ws+OFF_BIG0, ws+OFF_BIG1, ws+OFF_BIG2};
    float* fyr = ws+OFF_FYR; float* fyi = ws+OFF_FYI;
    float* fxr = ws+OFF_FXR; float* fxi = ws+OFF_FXI;
    float* gr  = ws+OFF_GR;  float* gi  = ws+OFF_GI;

    k_tables<<<32,256,0,stream>>>(ws);
    k_fc0<<<2048,256,0,stream>>>(x, fc0w, fc0b, big[0]);

    // schedule: {in, out, res}; big[1] is always the t-buffer
    const int s_in [6] = {0,0,2,2,2,0};
    const int s_out[6] = {0,2,2,2,0,0};
    const int s_res[6] = {-1,-1,0,-1,-1,2};

    for (int blk=0; blk<6; ++blk){
        float* in   = big[s_in[blk]];
        float* outb = big[s_out[blk]];
        const float* resp = (s_res[blk] < 0) ? nullptr : big[s_res[blk]];
        k_ydft<<<4096,256,0,stream>>>(in, fyr, fyi);
        k_xdft<<<512,256,0,stream>>>(fyr, fyi, ws+OFF_TXC, fxr, fxi);
        k_modemix<<<512,256,0,stream>>>(fxr, fxi,
            w1r+blk*524288, w1i+blk*524288, w2r+blk*524288, w2i+blk*524288, gr, gi);
        // mlp1 folded in Fourier domain; write back into fxr/fxi (dead after modemix)
        k_mlp1mix<<<512,256,0,stream>>>(gr, gi, m1w+blk*1024, fxr, fxi);
        k_invfft<<<65536,256,0,stream>>>(fxr, fxi, ws+OFF_TIC, ws+OFF_TIS,
            ws+OFF_IYC, ws+OFF_IYS, m1b+blk*32, big[1]);
        k_pointmix<<<2048,256,0,stream>>>(big[1], in, resp, outb,
            m2w+blk*1024, m2b+blk*32, ww+blk*1024, wb+blk*32, bw+blk*64, bb+blk*32);
    }
    k_head<<<2048,256,0,stream>>>(big[0], fc1w, fc1b, fc2w, fc2b, (float*)d_out);
}

// Round 3
// 1674.215 us; speedup vs baseline: 1.1694x; 1.1694x over previous
//
#include <hip/hip_runtime.h>

// ---- problem constants ----
#define kB 4
#define kV 2
#define kS 256
#define kW 32
#define kM 16
#define kNB 6
#define kTIN 10
#define kSTEP 5

#define NPLANE 65536            // S*S
#define NBWV   (kB*kW*kV)       // 256
#define BIGN   (kB*kW*kV*NPLANE)// 16777216 floats per state buffer
#define CHS    (kV*NPLANE)      // channel stride = 131072

// ---- workspace layout (float offsets) ----
#define OFF_BIG0 0
#define OFF_BIG1 16777216
#define OFF_BIG2 33554432
#define OFF_FYR  50331648   // [bwv][ky16][x256] = 1048576
#define OFF_FYI  51380224
#define OFF_FXR  52428800   // [b][ch][v][ky16][j32] = 131072
#define OFF_FXI  52559872
#define OFF_GR   52690944
#define OFF_GI   52822016
#define OFF_TXC  52953088   // xdft fwd [x][j]  8192
#define OFF_TXS  52961280
#define OFF_TIC  52969472   // x inverse [j][x] 8192
#define OFF_TIS  52977664
#define OFF_IYC  52985856   // y inverse [k][y] 4096
#define OFF_IYS  52989952
#define OFF_W1T  52994048   // fc1 weights transposed [o256][c32] = 8192
// total 53002240 floats ~= 202.2 MiB

__device__ __forceinline__ float gelu_f(float x){
    return 0.5f*x*(1.0f+erff(x*0.7071067811865476f));
}

// ---- DFT tables + fc1 transpose (double trig for accuracy) ----
__global__ void k_tables(float* ws, const float* __restrict__ fc1w){
    const double PI = 3.14159265358979323846;
    int t = blockIdx.x*256 + threadIdx.x; // 8192 threads
    if (t < 8192){
        // forward x-DFT, [x][j]: e^{-i 2pi kx x /256}
        int x = t>>5, j = t&31;
        int kx = (j<16) ? j : (224+j);
        int p = (kx*x)&255;
        double a = (double)p*(PI/128.0);
        ws[OFF_TXC+t] = (float)cos(a);
        ws[OFF_TXS+t] = -(float)sin(a);
        // inverse x-DFT, [j][x]: e^{+i 2pi kx x /256}
        int j2 = t>>8, x2 = t&255;
        int kx2 = (j2<16) ? j2 : (224+j2);
        int p2 = (kx2*x2)&255;
        double a2 = (double)p2*(PI/128.0);
        ws[OFF_TIC+t] = (float)cos(a2);
        ws[OFF_TIS+t] = (float)sin(a2);
        // fc1 transpose: w1t[o*32+c] = fc1w[c*256+o]
        int o = t>>5, c = t&31;
        ws[OFF_W1T+t] = fc1w[c*256+o];
    }
    if (t < 4096){
        // y-irfft basis [k][y], scale 1/65536 folds both ifft normalizations
        int k = t>>8, y = t&255;
        int p = (k*y)&255;
        double a = (double)p*(PI/128.0);
        float sc = 1.0f/65536.0f;
        ws[OFF_IYC+t] = (k==0 ? 1.0f : 2.0f*(float)cos(a))*sc;
        ws[OFF_IYS+t] = (k==0 ? 0.0f : -2.0f*(float)sin(a))*sc;
    }
}

// ---- fc0 + grid concat + transpose to (B,W,V,S,S) ----
__global__ void k_fc0(const float* __restrict__ x, const float* __restrict__ w,
                      const float* __restrict__ bias, float* __restrict__ h0){
    int plane = blockIdx.x>>8, xr = blockIdx.x&255, y = threadIdx.x;
    int xy = xr*256+y;
    long p = (long)plane*NPLANE + xy;
    float f[12];
    #pragma unroll
    for (int i=0;i<10;i++) f[i]=x[p*10+i];
    f[10] = 9.5f + xr*(1.0f/255.0f);
    f[11] = -0.5f + y*(1.0f/255.0f);
    float acc[32];
    #pragma unroll
    for (int o=0;o<32;o++) acc[o]=bias[o];
    #pragma unroll
    for (int c=0;c<12;c++){
        float fv=f[c];
        #pragma unroll
        for (int o=0;o<32;o++) acc[o]+=fv*w[c*32+o];
    }
    int b=plane>>1, v=plane&1;
    int base = b*(kW*CHS) + v*NPLANE + xy;
    #pragma unroll
    for (int o=0;o<32;o++) h0[base + o*CHS]=acc[o];
}

// ---- forward y-DFT: h (bwv,x,y) -> Fy[bwv][ky][x], rotation recurrence ----
__global__ void k_ydft(const float* __restrict__ h, float* __restrict__ fyr, float* __restrict__ fyi){
    __shared__ float hl[16*257];
    __shared__ float rr[16*17], ri[16*17];
    const double PI = 3.14159265358979323846;
    int bwv = blockIdx.x>>4, x0 = (blockIdx.x&15)<<4;
    int tid = threadIdx.x;
    const float* src = h + bwv*NPLANE + x0*256;
    for (int l=tid;l<4096;l+=256) hl[(l>>8)*257+(l&255)] = src[l];
    __syncthreads();
    int xi = tid>>4, k = tid&15;
    double a = (double)k*(PI/128.0);
    float cs = (float)cos(a), sn = -(float)sin(a); // step e^{-i 2pi k/256}
    float c = 1.0f, s = 0.0f, re = 0.0f, im = 0.0f;
    const float* row = hl + xi*257;
    #pragma unroll 8
    for (int y=0;y<256;y++){
        float av = row[y];
        re += av*c; im += av*s;
        float c2 = c*cs - s*sn;
        s = c*sn + s*cs; c = c2;
    }
    rr[xi*17+k]=re; ri[xi*17+k]=im;
    __syncthreads();
    int k2 = tid>>4, xi2 = tid&15;
    int o = bwv*4096 + k2*256 + x0+xi2;
    fyr[o]=rr[xi2*17+k2]; fyi[o]=ri[xi2*17+k2];
}

// ---- forward x-DFT: Fy row (256 x complex) -> 32 kx modes ----
__global__ void k_xdft(const float* __restrict__ fyr, const float* __restrict__ fyi,
                       const float* __restrict__ tab, float* __restrict__ fxr, float* __restrict__ fxi){
    int gid = blockIdx.x*256+threadIdx.x; // 131072
    int r = gid>>5, j = gid&31;
    const float* ar = fyr + r*256;
    const float* ai = fyi + r*256;
    const float* xc = tab;          // [x][j]
    const float* xs = tab + 8192;   // -sin
    float re=0.f, im=0.f;
    #pragma unroll 4
    for (int x=0;x<256;x++){
        float a=ar[x], b=ai[x];
        float c=xc[x*32+j], s=xs[x*32+j];
        re += a*c - b*s;
        im += a*s + b*c;
    }
    int o = ((r>>4)<<9) + ((r&15)<<5) + j; // [bwv][ky][j]
    fxr[o]=re; fxi[o]=im;
}

// ---- complex mode mixing with w1 (kx<16) / w2 (kx>=240) ----
__global__ void k_modemix(const float* __restrict__ fxr, const float* __restrict__ fxi,
                          const float* __restrict__ w1r_, const float* __restrict__ w1i_,
                          const float* __restrict__ w2r_, const float* __restrict__ w2i_,
                          float* __restrict__ gr, float* __restrict__ gi){
    int gid = blockIdx.x*256+threadIdx.x; // 131072: [b][o][v][ky][j]
    int j = gid&31, ky=(gid>>5)&15, v=(gid>>9)&1, o=(gid>>10)&31, b=gid>>15;
    int kxi = (j<16) ? j : (j-16);
    const float* wr_ = (j<16) ? w1r_ : w2r_;
    const float* wi_ = (j<16) ? w1i_ : w2i_;
    int wbase = (o*kV + v)*256 + kxi*16 + ky;         // + i*16384
    int fbase = (b*kW*kV + v)*512 + ky*32 + j;        // + i*1024
    float re=0.f, im=0.f;
    #pragma unroll 8
    for (int i=0;i<32;i++){
        float fr=fxr[fbase+i*1024], fi=fxi[fbase+i*1024];
        float wr=wr_[wbase+i*16384], wi=wi_[wbase+i*16384];
        re += fr*wr - fi*wi;
        im += fr*wi + fi*wr;
    }
    gr[gid]=re; gi[gid]=im;
}

// ---- fold mlp1 (channel-linear) into Fourier domain ----
__global__ void k_mlp1mix(const float* __restrict__ gr, const float* __restrict__ gi,
                          const float* __restrict__ m1, float* __restrict__ g2r, float* __restrict__ g2i){
    int gid = blockIdx.x*256+threadIdx.x; // 131072
    int r = gid & 1023;        // (v,ky,j)
    int o2 = (gid>>10)&31;
    int b = gid>>15;
    int base = b*32768 + r;
    float re=0.f, im=0.f;
    #pragma unroll 8
    for (int i=0;i<32;i++){
        float m = m1[o2*32+i];
        re += m*gr[base+i*1024];
        im += m*gi[base+i*1024];
    }
    g2r[gid]=re; g2i[gid]=im;
}

// ---- fused inverse: x-iDFT + y-irfft + mlp1 bias + gelu, register-tiled ----
// grid: 4096 blocks = bwv(256) x xtile(16); 256 threads
__global__ void k_invfft(const float* __restrict__ g2r, const float* __restrict__ g2i,
                         const float* __restrict__ xic, const float* __restrict__ xis,
                         const float* __restrict__ iyc, const float* __restrict__ iys,
                         const float* __restrict__ b1, float* __restrict__ tout){
    __shared__ float g2rl[16*33], g2il[16*33];   // [ky][j] padded
    __shared__ float frl[16*17], fil[16*17];     // [k][xi] padded
    int bwv = blockIdx.x>>4, x0 = (blockIdx.x&15)<<4;
    int tid = threadIdx.x;
    // load g2 for this bwv
    for (int l=tid;l<512;l+=256){
        g2rl[(l>>5)*33+(l&31)] = g2r[bwv*512+l];
        g2il[(l>>5)*33+(l&31)] = g2i[bwv*512+l];
    }
    __syncthreads();
    // phase 1: all 256 threads -> one (xi,k) pair each
    {
        int xi = tid>>4, k = tid&15;
        int x = x0 + xi;
        float re=0.f, im=0.f;
        #pragma unroll 8
        for (int j=0;j<32;j++){
            float grv=g2rl[k*33+j], giv=g2il[k*33+j];
            float c=xic[j*256+x], s=xis[j*256+x]; // e^{+i theta}
            re += grv*c - giv*s;
            im += grv*s + giv*c;
        }
        frl[k*17+xi]=re; fil[k*17+xi]=im;
    }
    __syncthreads();
    // phase 2: 4 xi x 4 y register tile per thread
    int wv = tid>>6, lane = tid&63;
    int w = (bwv>>1)&31;
    float bias = b1[w];
    float acc[4][4];
    #pragma unroll
    for (int a=0;a<4;a++)
        #pragma unroll
        for (int bq=0;bq<4;bq++) acc[a][bq]=0.f;
    #pragma unroll 4
    for (int k=0;k<16;k++){
        float4 yc = *reinterpret_cast<const float4*>(&iyc[k*256 + lane*4]);
        float4 ys = *reinterpret_cast<const float4*>(&iys[k*256 + lane*4]);
        #pragma unroll
        for (int xx=0;xx<4;xx++){
            float fr_ = frl[k*17 + wv*4+xx];
            float fi_ = fil[k*17 + wv*4+xx];
            acc[xx][0] += fr_*yc.x + fi_*ys.x;
            acc[xx][1] += fr_*yc.y + fi_*ys.y;
            acc[xx][2] += fr_*yc.z + fi_*ys.z;
            acc[xx][3] += fr_*yc.w + fi_*ys.w;
        }
    }
    float* outb = tout + bwv*NPLANE + lane*4;
    #pragma unroll
    for (int xx=0;xx<4;xx++){
        float4 o4;
        o4.x = gelu_f(bias+acc[xx][0]);
        o4.y = gelu_f(bias+acc[xx][1]);
        o4.z = gelu_f(bias+acc[xx][2]);
        o4.w = gelu_f(bias+acc[xx][3]);
        *reinterpret_cast<float4*>(&outb[(x0+wv*4+xx)*256]) = o4;
    }
}

// ---- fused pointwise: mlp2(t) + ww*h + grid-term, gelu, optional residual ----
// Weights read with wave-uniform indices -> scalar loads; no LDS.
// out may equal h (in-place): t/h fully read into registers before stores.
__global__ void k_pointmix(const float* __restrict__ t, const float* h, const float* res, float* out,
                           const float* __restrict__ m2, const float* __restrict__ b2,
                           const float* __restrict__ ww_, const float* __restrict__ wb_,
                           const float* __restrict__ bw_, const float* __restrict__ bb_){
    int plane=blockIdx.x>>8, xr=blockIdx.x&255, y=threadIdx.x;
    int b=plane>>1, v=plane&1, xy=xr*256+y;
    int pbase = b*(kW*CHS) + v*NPLANE + xy;
    float gx = 9.5f + xr*(1.0f/255.0f);
    float gy = -0.5f + y*(1.0f/255.0f);
    float tv[32], hv[32];
    #pragma unroll
    for (int c=0;c<32;c++) tv[c]=t[pbase + c*CHS];
    #pragma unroll
    for (int c=0;c<32;c++) hv[c]=h[pbase + c*CHS];
    #pragma unroll 4
    for (int o=0;o<32;o++){
        float s = b2[o]+wb_[o]+bb_[o] + bw_[o*2]*gx + bw_[o*2+1]*gy;
        #pragma unroll
        for (int c=0;c<32;c++) s += tv[c]*m2[o*32+c];
        #pragma unroll
        for (int c=0;c<32;c++) s += hv[c]*ww_[o*32+c];
        float r = gelu_f(s);
        if (res) r += res[pbase+o*CHS];
        out[pbase+o*CHS] = r;
    }
}

// ---- head: fc1(32->256) + gelu + fc2(256->5); weights via scalar loads ----
__global__ void k_head(const float* __restrict__ h, const float* __restrict__ w1t,
                       const float* __restrict__ fc1b, const float* __restrict__ fc2w,
                       const float* __restrict__ fc2b, float* __restrict__ out){
    int plane=blockIdx.x>>8, xr=blockIdx.x&255, y=threadIdx.x;
    int b=plane>>1, v=plane&1, xy=xr*256+y;
    int pbase = b*(kW*CHS) + v*NPLANE + xy;
    float hv[32];
    #pragma unroll
    for (int c=0;c<32;c++) hv[c]=h[pbase+c*CHS];
    float acc5[5];
    #pragma unroll
    for (int j=0;j<5;j++) acc5[j]=fc2b[j];
    #pragma unroll 4
    for (int o=0;o<256;o++){
        float s=fc1b[o];
        #pragma unroll
        for (int c=0;c<32;c++) s+=hv[c]*w1t[o*32+c];
        s=gelu_f(s);
        #pragma unroll
        for (int j=0;j<5;j++) acc5[j]+=s*fc2w[o*5+j];
    }
    long obase = ((long)plane*NPLANE + xy)*5;
    #pragma unroll
    for (int j=0;j<5;j++) out[obase+j]=acc5[j];
}

extern "C" void kernel_launch(void* const* d_in, const int* in_sizes, int n_in,
                              void* d_out, int out_size, void* d_ws, size_t ws_size,
                              hipStream_t stream){
    const float* x    =(const float*)d_in[0];
    const float* fc0w =(const float*)d_in[1];
    const float* fc0b =(const float*)d_in[2];
    const float* w1r  =(const float*)d_in[3];
    const float* w1i  =(const float*)d_in[4];
    const float* w2r  =(const float*)d_in[5];
    const float* w2i  =(const float*)d_in[6];
    const float* m1w  =(const float*)d_in[7];
    const float* m1b  =(const float*)d_in[8];
    const float* m2w  =(const float*)d_in[9];
    const float* m2b  =(const float*)d_in[10];
    const float* ww   =(const float*)d_in[11];
    const float* wb   =(const float*)d_in[12];
    const float* bw   =(const float*)d_in[13];
    const float* bb   =(const float*)d_in[14];
    const float* fc1w =(const float*)d_in[15];
    const float* fc1b =(const float*)d_in[16];
    const float* fc2w =(const float*)d_in[17];
    const float* fc2b =(const float*)d_in[18];

    float* ws = (float*)d_ws;
    float* big[3] = {ws+OFF_BIG0, ws+OFF_BIG1, ws+OFF_BIG2};
    float* fyr = ws+OFF_FYR; float* fyi = ws+OFF_FYI;
    float* fxr = ws+OFF_FXR; float* fxi = ws+OFF_FXI;
    float* gr  = ws+OFF_GR;  float* gi  = ws+OFF_GI;

    k_tables<<<32,256,0,stream>>>(ws, fc1w);
    k_fc0<<<2048,256,0,stream>>>(x, fc0w, fc0b, big[0]);

    // schedule: {in, out, res}; big[1] is always the t-buffer
    const int s_in [6] = {0,0,2,2,2,0};
    const int s_out[6] = {0,2,2,2,0,0};
    const int s_res[6] = {-1,-1,0,-1,-1,2};

    for (int blk=0; blk<6; ++blk){
        float* in   = big[s_in[blk]];
        float* outb = big[s_out[blk]];
        const float* resp = (s_res[blk] < 0) ? nullptr : big[s_res[blk]];
        k_ydft<<<4096,256,0,stream>>>(in, fyr, fyi);
        k_xdft<<<512,256,0,stream>>>(fyr, fyi, ws+OFF_TXC, fxr, fxi);
        k_modemix<<<512,256,0,stream>>>(fxr, fxi,
            w1r+blk*524288, w1i+blk*524288, w2r+blk*524288, w2i+blk*524288, gr, gi);
        // mlp1 folded in Fourier domain; write back into fxr/fxi (dead after modemix)
        k_mlp1mix<<<512,256,0,stream>>>(gr, gi, m1w+blk*1024, fxr, fxi);
        k_invfft<<<4096,256,0,stream>>>(fxr, fxi, ws+OFF_TIC, ws+OFF_TIS,
            ws+OFF_IYC, ws+OFF_IYS, m1b+blk*32, big[1]);
        k_pointmix<<<2048,256,0,stream>>>(big[1], in, resp, outb,
            m2w+blk*1024, m2b+blk*32, ww+blk*1024, wb+blk*32, bw+blk*64, bb+blk*32);
    }
    k_head<<<2048,256,0,stream>>>(big[0], ws+OFF_W1T, fc1b, fc2w, fc2b, (float*)d_out);
}

// Round 4
// 1535.692 us; speedup vs baseline: 1.2749x; 1.0902x over previous
//
#include <hip/hip_runtime.h>

// ---- problem constants ----
#define kB 4
#define kV 2
#define kS 256
#define kW 32
#define kM 16
#define kNB 6
#define kTIN 10
#define kSTEP 5

#define NPLANE 65536            // S*S
#define NBWV   (kB*kW*kV)       // 256
#define BIGN   (kB*kW*kV*NPLANE)// 16777216 floats per state buffer
#define CHS    (kV*NPLANE)      // channel stride = 131072

// ---- workspace layout (float offsets) ----
#define OFF_BIG0 0
#define OFF_BIG1 16777216
#define OFF_BIG2 33554432
#define OFF_FYR  50331648   // [bwv][ky16][x256] = 1048576
#define OFF_FYI  51380224
#define OFF_FXR  52428800   // [b][ch][v][ky16][j32] = 131072
#define OFF_FXI  52559872
#define OFF_GR   52690944
#define OFF_GI   52822016
#define OFF_TXC  52953088   // xdft fwd [x][j]  8192
#define OFF_TXS  52961280
#define OFF_TIC  52969472   // x inverse [j][x] 8192
#define OFF_TIS  52977664
#define OFF_IYC  52985856   // y inverse [k][y] 4096
#define OFF_IYS  52989952
#define OFF_W1T  52994048   // fc1 weights transposed [o256][c32] = 8192
// total 53002240 floats ~= 202.2 MiB

// Fast exact-erf gelu: A&S 7.1.26, |erf err| <= 1.5e-7. Native rcp+exp.
__device__ __forceinline__ float gelu_f(float x){
    float z = fabsf(x) * 0.70710678118654752f;
    float t = __builtin_amdgcn_rcpf(1.0f + 0.3275911f*z);
    float poly = t*(0.254829592f + t*(-0.284496736f + t*(1.421413741f + t*(-1.453152027f + t*1.061405429f))));
    float e = __expf(-z*z);
    float erf_abs = 1.0f - poly*e;
    float ph = (x >= 0.0f) ? (1.0f + erf_abs) : (1.0f - erf_abs);
    return 0.5f * x * ph;
}

// ---- DFT tables + fc1 transpose (double trig for accuracy) ----
__global__ void k_tables(float* ws, const float* __restrict__ fc1w){
    const double PI = 3.14159265358979323846;
    int t = blockIdx.x*256 + threadIdx.x; // 8192 threads
    if (t < 8192){
        // forward x-DFT, [x][j]: e^{-i 2pi kx x /256}
        int x = t>>5, j = t&31;
        int kx = (j<16) ? j : (224+j);
        int p = (kx*x)&255;
        double a = (double)p*(PI/128.0);
        ws[OFF_TXC+t] = (float)cos(a);
        ws[OFF_TXS+t] = -(float)sin(a);
        // inverse x-DFT, [j][x]: e^{+i 2pi kx x /256}
        int j2 = t>>8, x2 = t&255;
        int kx2 = (j2<16) ? j2 : (224+j2);
        int p2 = (kx2*x2)&255;
        double a2 = (double)p2*(PI/128.0);
        ws[OFF_TIC+t] = (float)cos(a2);
        ws[OFF_TIS+t] = (float)sin(a2);
        // fc1 transpose: w1t[o*32+c] = fc1w[c*256+o]
        int o = t>>5, c = t&31;
        ws[OFF_W1T+t] = fc1w[c*256+o];
    }
    if (t < 4096){
        // y-irfft basis [k][y], scale 1/65536 folds both ifft normalizations
        int k = t>>8, y = t&255;
        int p = (k*y)&255;
        double a = (double)p*(PI/128.0);
        float sc = 1.0f/65536.0f;
        ws[OFF_IYC+t] = (k==0 ? 1.0f : 2.0f*(float)cos(a))*sc;
        ws[OFF_IYS+t] = (k==0 ? 0.0f : -2.0f*(float)sin(a))*sc;
    }
}

// ---- fc0 + grid concat + transpose to (B,W,V,S,S) ----
__global__ void k_fc0(const float* __restrict__ x, const float* __restrict__ w,
                      const float* __restrict__ bias, float* __restrict__ h0){
    int plane = blockIdx.x>>8, xr = blockIdx.x&255, y = threadIdx.x;
    int xy = xr*256+y;
    long p = (long)plane*NPLANE + xy;
    float f[12];
    #pragma unroll
    for (int i=0;i<10;i++) f[i]=x[p*10+i];
    f[10] = 9.5f + xr*(1.0f/255.0f);
    f[11] = -0.5f + y*(1.0f/255.0f);
    float acc[32];
    #pragma unroll
    for (int o=0;o<32;o++) acc[o]=bias[o];
    #pragma unroll
    for (int c=0;c<12;c++){
        float fv=f[c];
        #pragma unroll
        for (int o=0;o<32;o++) acc[o]+=fv*w[c*32+o];
    }
    int b=plane>>1, v=plane&1;
    int base = b*(kW*CHS) + v*NPLANE + xy;
    #pragma unroll
    for (int o=0;o<32;o++) h0[base + o*CHS]=acc[o];
}

// ---- forward y-DFT, radix-4 u-split rotation ----
// f[k] = sum_u e^{-i th k u} * F_u,  F_u = sum_m a[4m+u] e^{-i 4 th k m}
__global__ void k_ydft(const float* __restrict__ h, float* __restrict__ fyr, float* __restrict__ fyi){
    __shared__ float hl[16*260];                 // row pad 260 keeps float4 16B-aligned
    __shared__ float rr[16*17], ri[16*17];
    const double PI = 3.14159265358979323846;
    int bwv = blockIdx.x>>4, x0 = (blockIdx.x&15)<<4;
    int tid = threadIdx.x;
    const float* src = h + bwv*NPLANE + x0*256;
    for (int l=tid;l<4096;l+=256) hl[(l>>8)*260+(l&255)] = src[l];
    __syncthreads();
    int xi = tid>>4, k = tid&15;
    double a1 = (double)k*(PI/128.0);
    float t1c = (float)cos(a1), t1s = -(float)sin(a1);   // e^{-i th k}
    double a4 = (double)k*(PI/32.0);
    float c4 = (float)cos(a4), s4 = -(float)sin(a4);     // e^{-i 4 th k}
    float t2c = t1c*t1c - t1s*t1s, t2s = 2.0f*t1c*t1s;   // e^{-i 2 th k}
    float t3c = t2c*t1c - t2s*t1s, t3s = t2c*t1s + t2s*t1c; // e^{-i 3 th k}
    float c = 1.0f, s = 0.0f;
    float re0=0.f,im0=0.f,re1=0.f,im1=0.f,re2=0.f,im2=0.f,re3=0.f,im3=0.f;
    const float* row = hl + xi*260;
    #pragma unroll 4
    for (int m=0;m<64;m++){
        float4 av = *reinterpret_cast<const float4*>(&row[m*4]);
        re0 += av.x*c; im0 += av.x*s;
        re1 += av.y*c; im1 += av.y*s;
        re2 += av.z*c; im2 += av.z*s;
        re3 += av.w*c; im3 += av.w*s;
        float c2_ = c*c4 - s*s4;
        s = c*s4 + s*c4; c = c2_;
    }
    float re = re0 + t1c*re1 - t1s*im1 + t2c*re2 - t2s*im2 + t3c*re3 - t3s*im3;
    float im = im0 + t1c*im1 + t1s*re1 + t2c*im2 + t2s*re2 + t3c*im3 + t3s*re3;
    rr[xi*17+k]=re; ri[xi*17+k]=im;
    __syncthreads();
    int k2 = tid>>4, xi2 = tid&15;
    int o = bwv*4096 + k2*256 + x0+xi2;
    fyr[o]=rr[xi2*17+k2]; fyi[o]=ri[xi2*17+k2];
}

// ---- forward x-DFT: Fy row (256 x complex) -> 32 kx modes ----
__global__ void k_xdft(const float* __restrict__ fyr, const float* __restrict__ fyi,
                       const float* __restrict__ tab, float* __restrict__ fxr, float* __restrict__ fxi){
    int gid = blockIdx.x*256+threadIdx.x; // 131072
    int r = gid>>5, j = gid&31;
    const float* ar = fyr + r*256;
    const float* ai = fyi + r*256;
    const float* xc = tab;          // [x][j]
    const float* xs = tab + 8192;   // -sin
    float re=0.f, im=0.f;
    #pragma unroll 8
    for (int x=0;x<256;x++){
        float a=ar[x], b=ai[x];
        float c=xc[x*32+j], s=xs[x*32+j];
        re += a*c - b*s;
        im += a*s + b*c;
    }
    int o = ((r>>4)<<9) + ((r&15)<<5) + j; // [bwv][ky][j]
    fxr[o]=re; fxi[o]=im;
}

// ---- complex mode mixing (w1/w2) with mlp1 fused via LDS ----
// grid: 128 blocks = (b4, v2, ky16); 1024 threads = (o32, j32)
__global__ void k_modemix(const float* __restrict__ fxr, const float* __restrict__ fxi,
                          const float* __restrict__ w1r_, const float* __restrict__ w1i_,
                          const float* __restrict__ w2r_, const float* __restrict__ w2i_,
                          const float* __restrict__ m1, float* __restrict__ g2r, float* __restrict__ g2i){
    __shared__ float glr[32*33], gli[32*33];
    int blk = blockIdx.x;
    int b = blk>>5, v = (blk>>4)&1, ky = blk&15;
    int o = threadIdx.x>>5, j = threadIdx.x&31;
    int kxi = (j<16) ? j : (j-16);
    const float* wr_ = (j<16) ? w1r_ : w2r_;
    const float* wi_ = (j<16) ? w1i_ : w2i_;
    int wbase = (o*kV + v)*256 + kxi*16 + ky;         // + i*16384
    int fbase = (b*kW*kV + v)*512 + ky*32 + j;        // + i*1024
    float re=0.f, im=0.f;
    #pragma unroll 8
    for (int i=0;i<32;i++){
        float fr=fxr[fbase+i*1024], fi=fxi[fbase+i*1024];
        float wr=wr_[wbase+i*16384], wi=wi_[wbase+i*16384];
        re += fr*wr - fi*wi;
        im += fr*wi + fi*wr;
    }
    glr[o*33+j]=re; gli[o*33+j]=im;
    __syncthreads();
    // mlp1: g2[o] = sum_i m1[o][i] * g[i]
    float r2=0.f, i2=0.f;
    #pragma unroll 8
    for (int i=0;i<32;i++){
        float m = m1[o*32+i];
        r2 += m*glr[i*33+j];
        i2 += m*gli[i*33+j];
    }
    int gid = ((b*kW + o)*kV + v)*512 + ky*32 + j;
    g2r[gid]=r2; g2i[gid]=i2;
}

// ---- fused inverse: x-iDFT + y-irfft + mlp1 bias + gelu, register-tiled ----
// grid: 4096 blocks = bwv(256) x xtile(16); 256 threads
__global__ void k_invfft(const float* __restrict__ g2r, const float* __restrict__ g2i,
                         const float* __restrict__ xic, const float* __restrict__ xis,
                         const float* __restrict__ iyc, const float* __restrict__ iys,
                         const float* __restrict__ b1, float* __restrict__ tout){
    __shared__ float g2rl[16*33], g2il[16*33];   // [ky][j] padded
    __shared__ float frl[16*17], fil[16*17];     // [k][xi] padded
    int bwv = blockIdx.x>>4, x0 = (blockIdx.x&15)<<4;
    int tid = threadIdx.x;
    for (int l=tid;l<512;l+=256){
        g2rl[(l>>5)*33+(l&31)] = g2r[bwv*512+l];
        g2il[(l>>5)*33+(l&31)] = g2i[bwv*512+l];
    }
    __syncthreads();
    {
        int xi = tid>>4, k = tid&15;
        int x = x0 + xi;
        float re=0.f, im=0.f;
        #pragma unroll 8
        for (int j=0;j<32;j++){
            float grv=g2rl[k*33+j], giv=g2il[k*33+j];
            float c=xic[j*256+x], s=xis[j*256+x]; // e^{+i theta}
            re += grv*c - giv*s;
            im += grv*s + giv*c;
        }
        frl[k*17+xi]=re; fil[k*17+xi]=im;
    }
    __syncthreads();
    int wv = tid>>6, lane = tid&63;
    int w = (bwv>>1)&31;
    float bias = b1[w];
    float acc[4][4];
    #pragma unroll
    for (int a=0;a<4;a++)
        #pragma unroll
        for (int bq=0;bq<4;bq++) acc[a][bq]=0.f;
    #pragma unroll 4
    for (int k=0;k<16;k++){
        float4 yc = *reinterpret_cast<const float4*>(&iyc[k*256 + lane*4]);
        float4 ys = *reinterpret_cast<const float4*>(&iys[k*256 + lane*4]);
        #pragma unroll
        for (int xx=0;xx<4;xx++){
            float fr_ = frl[k*17 + wv*4+xx];
            float fi_ = fil[k*17 + wv*4+xx];
            acc[xx][0] += fr_*yc.x + fi_*ys.x;
            acc[xx][1] += fr_*yc.y + fi_*ys.y;
            acc[xx][2] += fr_*yc.z + fi_*ys.z;
            acc[xx][3] += fr_*yc.w + fi_*ys.w;
        }
    }
    float* outb = tout + bwv*NPLANE + lane*4;
    #pragma unroll
    for (int xx=0;xx<4;xx++){
        float4 o4;
        o4.x = gelu_f(bias+acc[xx][0]);
        o4.y = gelu_f(bias+acc[xx][1]);
        o4.z = gelu_f(bias+acc[xx][2]);
        o4.w = gelu_f(bias+acc[xx][3]);
        *reinterpret_cast<float4*>(&outb[(x0+wv*4+xx)*256]) = o4;
    }
}

// ---- fused pointwise: mlp2(t) + ww*h + grid-term, gelu, optional residual ----
__global__ void k_pointmix(const float* __restrict__ t, const float* h, const float* res, float* out,
                           const float* __restrict__ m2, const float* __restrict__ b2,
                           const float* __restrict__ ww_, const float* __restrict__ wb_,
                           const float* __restrict__ bw_, const float* __restrict__ bb_){
    int plane=blockIdx.x>>8, xr=blockIdx.x&255, y=threadIdx.x;
    int b=plane>>1, v=plane&1, xy=xr*256+y;
    int pbase = b*(kW*CHS) + v*NPLANE + xy;
    float gx = 9.5f + xr*(1.0f/255.0f);
    float gy = -0.5f + y*(1.0f/255.0f);
    float tv[32], hv[32];
    #pragma unroll
    for (int c=0;c<32;c++) tv[c]=t[pbase + c*CHS];
    #pragma unroll
    for (int c=0;c<32;c++) hv[c]=h[pbase + c*CHS];
    #pragma unroll 4
    for (int o=0;o<32;o++){
        float s = b2[o]+wb_[o]+bb_[o] + bw_[o*2]*gx + bw_[o*2+1]*gy;
        #pragma unroll
        for (int c=0;c<32;c++) s += tv[c]*m2[o*32+c];
        #pragma unroll
        for (int c=0;c<32;c++) s += hv[c]*ww_[o*32+c];
        float r = gelu_f(s);
        if (res) r += res[pbase+o*CHS];
        out[pbase+o*CHS] = r;
    }
}

// ---- head: fc1(32->256) + gelu + fc2(256->5); weights via scalar loads ----
__global__ void k_head(const float* __restrict__ h, const float* __restrict__ w1t,
                       const float* __restrict__ fc1b, const float* __restrict__ fc2w,
                       const float* __restrict__ fc2b, float* __restrict__ out){
    int plane=blockIdx.x>>8, xr=blockIdx.x&255, y=threadIdx.x;
    int b=plane>>1, v=plane&1, xy=xr*256+y;
    int pbase = b*(kW*CHS) + v*NPLANE + xy;
    float hv[32];
    #pragma unroll
    for (int c=0;c<32;c++) hv[c]=h[pbase+c*CHS];
    float acc5[5];
    #pragma unroll
    for (int j=0;j<5;j++) acc5[j]=fc2b[j];
    #pragma unroll 4
    for (int o=0;o<256;o++){
        float s=fc1b[o];
        #pragma unroll
        for (int c=0;c<32;c++) s+=hv[c]*w1t[o*32+c];
        s=gelu_f(s);
        #pragma unroll
        for (int j=0;j<5;j++) acc5[j]+=s*fc2w[o*5+j];
    }
    long obase = ((long)plane*NPLANE + xy)*5;
    #pragma unroll
    for (int j=0;j<5;j++) out[obase+j]=acc5[j];
}

extern "C" void kernel_launch(void* const* d_in, const int* in_sizes, int n_in,
                              void* d_out, int out_size, void* d_ws, size_t ws_size,
                              hipStream_t stream){
    const float* x    =(const float*)d_in[0];
    const float* fc0w =(const float*)d_in[1];
    const float* fc0b =(const float*)d_in[2];
    const float* w1r  =(const float*)d_in[3];
    const float* w1i  =(const float*)d_in[4];
    const float* w2r  =(const float*)d_in[5];
    const float* w2i  =(const float*)d_in[6];
    const float* m1w  =(const float*)d_in[7];
    const float* m1b  =(const float*)d_in[8];
    const float* m2w  =(const float*)d_in[9];
    const float* m2b  =(const float*)d_in[10];
    const float* ww   =(const float*)d_in[11];
    const float* wb   =(const float*)d_in[12];
    const float* bw   =(const float*)d_in[13];
    const float* bb   =(const float*)d_in[14];
    const float* fc1w =(const float*)d_in[15];
    const float* fc1b =(const float*)d_in[16];
    const float* fc2w =(const float*)d_in[17];
    const float* fc2b =(const float*)d_in[18];

    float* ws = (float*)d_ws;
    float* big[3] = {ws+OFF_BIG0, ws+OFF_BIG1, ws+OFF_BIG2};
    float* fyr = ws+OFF_FYR; float* fyi = ws+OFF_FYI;
    float* fxr = ws+OFF_FXR; float* fxi = ws+OFF_FXI;
    float* gr  = ws+OFF_GR;  float* gi  = ws+OFF_GI;

    k_tables<<<32,256,0,stream>>>(ws, fc1w);
    k_fc0<<<2048,256,0,stream>>>(x, fc0w, fc0b, big[0]);

    // schedule: {in, out, res}; big[1] is always the t-buffer
    const int s_in [6] = {0,0,2,2,2,0};
    const int s_out[6] = {0,2,2,2,0,0};
    const int s_res[6] = {-1,-1,0,-1,-1,2};

    for (int blk=0; blk<6; ++blk){
        float* in   = big[s_in[blk]];
        float* outb = big[s_out[blk]];
        const float* resp = (s_res[blk] < 0) ? nullptr : big[s_res[blk]];
        k_ydft<<<4096,256,0,stream>>>(in, fyr, fyi);
        k_xdft<<<512,256,0,stream>>>(fyr, fyi, ws+OFF_TXC, fxr, fxi);
        k_modemix<<<128,1024,0,stream>>>(fxr, fxi,
            w1r+blk*524288, w1i+blk*524288, w2r+blk*524288, w2i+blk*524288,
            m1w+blk*1024, gr, gi);
        k_invfft<<<4096,256,0,stream>>>(gr, gi, ws+OFF_TIC, ws+OFF_TIS,
            ws+OFF_IYC, ws+OFF_IYS, m1b+blk*32, big[1]);
        k_pointmix<<<2048,256,0,stream>>>(big[1], in, resp, outb,
            m2w+blk*1024, m2b+blk*32, ww+blk*1024, wb+blk*32, bw+blk*64, bb+blk*32);
    }
    k_head<<<2048,256,0,stream>>>(big[0], ws+OFF_W1T, fc1b, fc2w, fc2b, (float*)d_out);
}